// Round 1
// baseline (636.204 us; speedup 1.0000x reference)
//
#include <hip/hip_runtime.h>
#include <cstdint>

#define NIMG 8
#define PRE 2000
#define POST 1000
#define NBINS 4096
#define CAND_CAP 8192
#define PAIR_CAP 12288
#define IMGW 800.0f
#define BBOX_CLIP_F 4.135166556742356f

// workspace layout (bytes)
#define OFF_HIST 0
#define OFF_INFO 131072
#define OFF_CCNT (OFF_INFO + 64)
#define OFF_PCNT (OFF_CCNT + 64)
#define ZERO_BYTES (OFF_PCNT + 64)              // 131264
#define OFF_CAND ZERO_BYTES                      // u64[8][8192] -> 524288
#define OFF_BOX  (OFF_CAND + NIMG*CAND_CAP*8)    // float[8][2000][4] -> 256000
#define OFF_SCORE (OFF_BOX + NIMG*PRE*16)
#define OFF_VALID (OFF_SCORE + NIMG*PRE*4)
#define OFF_PAIRS (OFF_VALID + NIMG*PRE*4)       // u32[8][12288]

__device__ __forceinline__ unsigned int fkey(float f) {
    unsigned int b = __float_as_uint(f);
    // monotone map: ascending float <-> ascending uint
    return (b & 0x80000000u) ? ~b : (b | 0x80000000u);
}

__global__ void k_zero(unsigned int* __restrict__ p, int n) {
    int i = blockIdx.x * blockDim.x + threadIdx.x;
    if (i < n) p[i] = 0u;
}

__global__ void k_hist(const float* __restrict__ obj, unsigned int* __restrict__ hist, int A) {
    __shared__ unsigned int h[NBINS];
    const int img = blockIdx.y;
    for (int i = threadIdx.x; i < NBINS; i += blockDim.x) h[i] = 0u;
    __syncthreads();
    const float4* p4 = (const float4*)(obj + (size_t)img * A);
    const int nvec = A >> 2;
    for (int i = blockIdx.x * blockDim.x + threadIdx.x; i < nvec; i += blockDim.x * gridDim.x) {
        float4 v = p4[i];
        atomicAdd(&h[fkey(v.x) >> 20], 1u);
        atomicAdd(&h[fkey(v.y) >> 20], 1u);
        atomicAdd(&h[fkey(v.z) >> 20], 1u);
        atomicAdd(&h[fkey(v.w) >> 20], 1u);
    }
    if (blockIdx.x == 0) {
        const float* p = obj + (size_t)img * A;
        for (int i = (nvec << 2) + threadIdx.x; i < A; i += blockDim.x)
            atomicAdd(&h[fkey(p[i]) >> 20], 1u);
    }
    __syncthreads();
    for (int i = threadIdx.x; i < NBINS; i += blockDim.x)
        if (h[i]) atomicAdd(&hist[img * NBINS + i], h[i]);
}

// find largest bin b with count(bins >= b) >= K  (unique crossing)
__global__ void k_scan(const unsigned int* __restrict__ hist, unsigned int* __restrict__ info, int K) {
    __shared__ unsigned int seg[256];
    __shared__ unsigned int sufx[256];
    const int img = blockIdx.x;
    const int t = threadIdx.x;
    const unsigned int* h = hist + img * NBINS;
    unsigned int loc[16];
    unsigned int s = 0;
#pragma unroll
    for (int k = 0; k < 16; ++k) { loc[k] = h[t * 16 + k]; s += loc[k]; }
    seg[t] = s;
    __syncthreads();
    if (t == 0) {
        unsigned int r = 0;
        for (int i = 255; i >= 0; --i) { sufx[i] = r; r += seg[i]; }
    }
    __syncthreads();
    unsigned int run = sufx[t];
#pragma unroll
    for (int k = 15; k >= 0; --k) {
        unsigned int nrun = run + loc[k];
        if (run < (unsigned int)K && nrun >= (unsigned int)K)
            info[img] = (unsigned int)(t * 16 + k);
        run = nrun;
    }
}

__global__ void k_compact(const float* __restrict__ obj, const unsigned int* __restrict__ info,
                          unsigned long long* __restrict__ cand, unsigned int* __restrict__ ccnt, int A) {
    const int img = blockIdx.y;
    const unsigned int kmin = info[img] << 20;
    const float4* p4 = (const float4*)(obj + (size_t)img * A);
    const int nvec = A >> 2;
    unsigned long long* c = cand + (size_t)img * CAND_CAP;
    for (int i = blockIdx.x * blockDim.x + threadIdx.x; i < nvec; i += blockDim.x * gridDim.x) {
        float4 v = p4[i];
        unsigned int k0 = fkey(v.x), k1 = fkey(v.y), k2 = fkey(v.z), k3 = fkey(v.w);
        unsigned int base = (unsigned int)(i << 2);
        if (k0 >= kmin) { unsigned int p = atomicAdd(ccnt + img, 1u); if (p < CAND_CAP) c[p] = ((unsigned long long)k0 << 32) | (0xFFFFFFFFu - base); }
        if (k1 >= kmin) { unsigned int p = atomicAdd(ccnt + img, 1u); if (p < CAND_CAP) c[p] = ((unsigned long long)k1 << 32) | (0xFFFFFFFFu - (base + 1u)); }
        if (k2 >= kmin) { unsigned int p = atomicAdd(ccnt + img, 1u); if (p < CAND_CAP) c[p] = ((unsigned long long)k2 << 32) | (0xFFFFFFFFu - (base + 2u)); }
        if (k3 >= kmin) { unsigned int p = atomicAdd(ccnt + img, 1u); if (p < CAND_CAP) c[p] = ((unsigned long long)k3 << 32) | (0xFFFFFFFFu - (base + 3u)); }
    }
    if (blockIdx.x == 0) {
        const float* p = obj + (size_t)img * A;
        for (int i = (nvec << 2) + threadIdx.x; i < A; i += blockDim.x) {
            unsigned int k = fkey(p[i]);
            if (k >= kmin) { unsigned int pp = atomicAdd(ccnt + img, 1u); if (pp < CAND_CAP) c[pp] = ((unsigned long long)k << 32) | (0xFFFFFFFFu - (unsigned int)i); }
        }
    }
}

// per-image: bitonic sort candidates desc (key, then smaller idx first) -> top-2000 -> decode/clip/valid
__global__ __launch_bounds__(1024) void k_sortdecode(
    const float* __restrict__ obj, const float* __restrict__ deltas, const float* __restrict__ anchors,
    const unsigned long long* __restrict__ cand, const unsigned int* __restrict__ ccnt,
    float* __restrict__ boxes, float* __restrict__ scores, unsigned int* __restrict__ valid, int A) {
    __shared__ unsigned long long sb[CAND_CAP];   // 64 KB
    const int img = blockIdx.x;
    const int t = threadIdx.x;
    int n = (int)ccnt[img];
    if (n > CAND_CAP) n = CAND_CAP;
    int Ns = 2048;
    while (Ns < n) Ns <<= 1;
    const unsigned long long* c = cand + (size_t)img * CAND_CAP;
    for (int i = t; i < Ns; i += 1024) sb[i] = (i < n) ? c[i] : 0ull;
    __syncthreads();
    for (int k = 2; k <= Ns; k <<= 1) {
        for (int j = k >> 1; j > 0; j >>= 1) {
            for (int i = t; i < Ns; i += 1024) {
                int l = i ^ j;
                if (l > i) {
                    unsigned long long a = sb[i], b = sb[l];
                    bool sw = ((i & k) == 0) ? (a < b) : (a > b);   // overall descending
                    if (sw) { sb[i] = b; sb[l] = a; }
                }
            }
            __syncthreads();
        }
    }
    for (int e = t; e < PRE; e += 1024) {
        unsigned long long v = sb[e];
        unsigned int idx = 0xFFFFFFFFu - (unsigned int)(v & 0xFFFFFFFFull);
        float logit = obj[(size_t)img * A + idx];
        float4 d = ((const float4*)deltas)[(size_t)img * A + idx];
        float4 a = ((const float4*)anchors)[idx];
        float wa = a.z - a.x, ha = a.w - a.y;
        float cxa = a.x + 0.5f * wa, cya = a.y + 0.5f * ha;
        float dw = fminf(d.z, BBOX_CLIP_F), dh = fminf(d.w, BBOX_CLIP_F);
        float pcx = d.x * wa + cxa, pcy = d.y * ha + cya;
        float pw = expf(dw) * wa, ph = expf(dh) * ha;
        float x1 = fminf(fmaxf(pcx - 0.5f * pw, 0.0f), IMGW);
        float y1 = fminf(fmaxf(pcy - 0.5f * ph, 0.0f), IMGW);
        float x2 = fminf(fmaxf(pcx + 0.5f * pw, 0.0f), IMGW);
        float y2 = fminf(fmaxf(pcy + 0.5f * ph, 0.0f), IMGW);
        float sc = 1.0f / (1.0f + expf(-logit));
        unsigned int vd = (((x2 - x1) >= 1e-3f) && ((y2 - y1) >= 1e-3f) && (sc > 0.0f)) ? 1u : 0u;
        ((float4*)boxes)[(size_t)img * PRE + e] = make_float4(x1, y1, x2, y2);
        scores[img * PRE + e] = sc;
        valid[img * PRE + e] = vd;
    }
}

// sparse suppression pairs: emit (i<j) with IoU > 0.7
__global__ void k_pairs(const float* __restrict__ boxes, unsigned int* __restrict__ pairs,
                        unsigned int* __restrict__ pcnt) {
#pragma clang fp contract(off)
    __shared__ float bx1[PRE], by1[PRE], bx2[PRE], by2[PRE], bar[PRE];
    const int img = blockIdx.y;
    const float4* B = (const float4*)(boxes + (size_t)img * PRE * 4);
    for (int i = threadIdx.x; i < PRE; i += blockDim.x) {
        float4 b = B[i];
        bx1[i] = b.x; by1[i] = b.y; bx2[i] = b.z; by2[i] = b.w;
        bar[i] = (b.z - b.x) * (b.w - b.y);
    }
    __syncthreads();
    unsigned int* pp = pairs + (size_t)img * PAIR_CAP;
    const int r0 = blockIdx.x * 63;
    const int r1 = min(r0 + 63, PRE);
    for (int i = r0; i < r1; ++i) {
        float x1 = bx1[i], y1 = by1[i], x2 = bx2[i], y2 = by2[i], ai = bar[i];
        for (int j = i + 1 + threadIdx.x; j < PRE; j += blockDim.x) {
            float xx1 = fmaxf(x1, bx1[j]);
            float yy1 = fmaxf(y1, by1[j]);
            float xx2 = fminf(x2, bx2[j]);
            float yy2 = fminf(y2, by2[j]);
            float iw = fmaxf(xx2 - xx1, 0.0f);
            float ih = fmaxf(yy2 - yy1, 0.0f);
            float inter = iw * ih;
            float iou = inter / (ai + bar[j] - inter + 1e-12f);
            if (iou > 0.7f) {
                unsigned int p = atomicAdd(pcnt + img, 1u);
                if (p < PAIR_CAP) pp[p] = ((unsigned int)i << 11) | (unsigned int)j;
            }
        }
    }
}

// per-image: sort pairs by (i,j), serial greedy apply, prefix-scan keep, write [1000,5]
__global__ __launch_bounds__(1024) void k_final(
    const float* __restrict__ boxes, const float* __restrict__ scores, const unsigned int* __restrict__ valid,
    const unsigned int* __restrict__ pairs, const unsigned int* __restrict__ pcnt, float* __restrict__ out) {
    __shared__ unsigned int pb[PAIR_CAP];     // 48 KB
    __shared__ unsigned char keep[2048];
    __shared__ unsigned int incl[2048];
    const int img = blockIdx.x;
    const int t = threadIdx.x;
    int np = (int)pcnt[img];
    if (np > PAIR_CAP) np = PAIR_CAP;
    int Np = 2;
    while (Np < np) Np <<= 1;
    const unsigned int* ps = pairs + (size_t)img * PAIR_CAP;
    for (int i = t; i < Np; i += 1024) pb[i] = (i < np) ? ps[i] : 0xFFFFFFFFu;
    for (int i = t; i < 2048; i += 1024) keep[i] = (i < PRE) ? (unsigned char)valid[img * PRE + i] : 0;
    __syncthreads();
    for (int k = 2; k <= Np; k <<= 1) {
        for (int j = k >> 1; j > 0; j >>= 1) {
            for (int i = t; i < Np; i += 1024) {
                int l = i ^ j;
                if (l > i) {
                    unsigned int a = pb[i], b = pb[l];
                    bool sw = ((i & k) == 0) ? (a > b) : (a < b);   // ascending
                    if (sw) { pb[i] = b; pb[l] = a; }
                }
            }
            __syncthreads();
        }
    }
    if (t == 0) {
        // greedy NMS: pairs sorted by i ascending; keep[i] is final when its pairs are processed
        for (int p = 0; p < np; ++p) {
            unsigned int u = pb[p];
            unsigned int i = u >> 11, j = u & 2047u;
            if (keep[i]) keep[j] = 0;
        }
    }
    __syncthreads();
    const int i0 = t, i1 = t + 1024;
    incl[i0] = keep[i0]; incl[i1] = keep[i1];
    __syncthreads();
    for (int d = 1; d < 2048; d <<= 1) {
        unsigned int v0 = (i0 >= d) ? incl[i0 - d] : 0u;
        unsigned int v1 = (i1 >= d) ? incl[i1 - d] : 0u;
        __syncthreads();
        incl[i0] += v0; incl[i1] += v1;
        __syncthreads();
    }
    const unsigned int Nk = incl[2047];
    for (int i = t; i < PRE; i += 1024) {
        int slot = -1;
        float sc = 0.0f;
        if (keep[i]) {
            unsigned int r = incl[i] - 1u;
            if (r < (unsigned int)POST) { slot = (int)r; sc = scores[img * PRE + i]; }
        } else if (Nk < (unsigned int)POST) {
            unsigned int rnk = (unsigned int)i - incl[i];      // non-kept rank (ascending index)
            unsigned int s2 = Nk + rnk;
            if (s2 < (unsigned int)POST) { slot = (int)s2; sc = 0.0f; }
        }
        if (slot >= 0) {
            float4 b = ((const float4*)boxes)[(size_t)img * PRE + i];
            float* o = out + ((size_t)img * POST + slot) * 5;
            o[0] = b.x; o[1] = b.y; o[2] = b.z; o[3] = b.w; o[4] = sc;
        }
    }
}

extern "C" void kernel_launch(void* const* d_in, const int* in_sizes, int n_in,
                              void* d_out, int out_size, void* d_ws, size_t ws_size,
                              hipStream_t stream) {
    const float* obj = (const float*)d_in[0];
    const float* deltas = (const float*)d_in[1];
    const float* anchors = (const float*)d_in[2];
    float* out = (float*)d_out;
    const int A = in_sizes[0] / NIMG;

    char* ws = (char*)d_ws;
    unsigned int* hist = (unsigned int*)(ws + OFF_HIST);
    unsigned int* info = (unsigned int*)(ws + OFF_INFO);
    unsigned int* ccnt = (unsigned int*)(ws + OFF_CCNT);
    unsigned int* pcnt = (unsigned int*)(ws + OFF_PCNT);
    unsigned long long* cand = (unsigned long long*)(ws + OFF_CAND);
    float* boxes = (float*)(ws + OFF_BOX);
    float* scores = (float*)(ws + OFF_SCORE);
    unsigned int* valid = (unsigned int*)(ws + OFF_VALID);
    unsigned int* pairs = (unsigned int*)(ws + OFF_PAIRS);

    const int nzero = ZERO_BYTES / 4;
    k_zero<<<dim3((nzero + 255) / 256), dim3(256), 0, stream>>>((unsigned int*)ws, nzero);
    k_hist<<<dim3(32, NIMG), dim3(256), 0, stream>>>(obj, hist, A);
    k_scan<<<dim3(NIMG), dim3(256), 0, stream>>>(hist, info, PRE);
    k_compact<<<dim3(32, NIMG), dim3(256), 0, stream>>>(obj, info, cand, ccnt, A);
    k_sortdecode<<<dim3(NIMG), dim3(1024), 0, stream>>>(obj, deltas, anchors, cand, ccnt, boxes, scores, valid, A);
    k_pairs<<<dim3(32, NIMG), dim3(256), 0, stream>>>(boxes, pairs, pcnt);
    k_final<<<dim3(NIMG), dim3(1024), 0, stream>>>(boxes, scores, valid, pairs, pcnt, out);
}

// Round 2
// 385.780 us; speedup vs baseline: 1.6491x; 1.6491x over previous
//
#include <hip/hip_runtime.h>
#include <cstdint>

#define NIMG 8
#define PRE 2000
#define POST 1000
#define NBINS 4096
#define CAND_CAP 8192
#define BLK_CAND_CAP 2048
#define PAIR_CAP 12288
#define BLK_PAIR_CAP 2048
#define IMGW 800.0f
#define BBOX_CLIP_F 4.135166556742356f

// workspace layout (bytes)
#define OFF_HIST 0
#define OFF_INFO 131072                          // 8 u32 (+pad)
#define OFF_CCNT (OFF_INFO + 64)                 // 8 counters @ 128B stride -> 1024
#define OFF_PCNT (OFF_CCNT + 1024)               // 8 counters @ 128B stride -> 1024
#define ZERO_BYTES (OFF_PCNT + 1024)
#define OFF_CAND ZERO_BYTES                      // u64[8][8192]
#define OFF_BOX  (OFF_CAND + NIMG*CAND_CAP*8)    // float[8][2000][4]
#define OFF_SCORE (OFF_BOX + NIMG*PRE*16)
#define OFF_VALID (OFF_SCORE + NIMG*PRE*4)
#define OFF_PAIRS (OFF_VALID + NIMG*PRE*4)       // u32[8][12288]

#define CNT_STRIDE 32                            // u32 units: 128 B between per-image counters

__device__ __forceinline__ unsigned int fkey(float f) {
    unsigned int b = __float_as_uint(f);
    // monotone map: ascending float <-> ascending uint
    return (b & 0x80000000u) ? ~b : (b | 0x80000000u);
}

__global__ void k_zero(unsigned int* __restrict__ p, int n) {
    int i = blockIdx.x * blockDim.x + threadIdx.x;
    if (i < n) p[i] = 0u;
}

__global__ void k_hist(const float* __restrict__ obj, unsigned int* __restrict__ hist, int A) {
    __shared__ unsigned int h[NBINS];
    const int img = blockIdx.y;
    for (int i = threadIdx.x; i < NBINS; i += blockDim.x) h[i] = 0u;
    __syncthreads();
    const float4* p4 = (const float4*)(obj + (size_t)img * A);
    const int nvec = A >> 2;
    for (int i = blockIdx.x * blockDim.x + threadIdx.x; i < nvec; i += blockDim.x * gridDim.x) {
        float4 v = p4[i];
        atomicAdd(&h[fkey(v.x) >> 20], 1u);
        atomicAdd(&h[fkey(v.y) >> 20], 1u);
        atomicAdd(&h[fkey(v.z) >> 20], 1u);
        atomicAdd(&h[fkey(v.w) >> 20], 1u);
    }
    if (blockIdx.x == 0) {
        const float* p = obj + (size_t)img * A;
        for (int i = (nvec << 2) + threadIdx.x; i < A; i += blockDim.x)
            atomicAdd(&h[fkey(p[i]) >> 20], 1u);
    }
    __syncthreads();
    for (int i = threadIdx.x; i < NBINS; i += blockDim.x)
        if (h[i]) atomicAdd(&hist[img * NBINS + i], h[i]);
}

// find largest bin b with count(bins >= b) >= K  (unique crossing)
__global__ void k_scan(const unsigned int* __restrict__ hist, unsigned int* __restrict__ info, int K) {
    __shared__ unsigned int seg[256];
    __shared__ unsigned int sufx[256];
    const int img = blockIdx.x;
    const int t = threadIdx.x;
    const unsigned int* h = hist + img * NBINS;
    unsigned int loc[16];
    unsigned int s = 0;
#pragma unroll
    for (int k = 0; k < 16; ++k) { loc[k] = h[t * 16 + k]; s += loc[k]; }
    seg[t] = s;
    __syncthreads();
    if (t == 0) {
        unsigned int r = 0;
        for (int i = 255; i >= 0; --i) { sufx[i] = r; r += seg[i]; }
    }
    __syncthreads();
    unsigned int run = sufx[t];
#pragma unroll
    for (int k = 15; k >= 0; --k) {
        unsigned int nrun = run + loc[k];
        if (run < (unsigned int)K && nrun >= (unsigned int)K)
            info[img] = (unsigned int)(t * 16 + k);
        run = nrun;
    }
}

// LDS-staged compaction: per-block shared buffer + ONE global atomic per block.
// (Round-1 lesson: 24k device atomics to one cacheline = 255 us of serialization.)
__global__ void k_compact(const float* __restrict__ obj, const unsigned int* __restrict__ info,
                          unsigned long long* __restrict__ cand, unsigned int* __restrict__ ccnt, int A) {
    __shared__ unsigned long long loc[BLK_CAND_CAP];   // 16 KB
    __shared__ unsigned int lcnt, gbase;
    const int img = blockIdx.y;
    if (threadIdx.x == 0) lcnt = 0u;
    __syncthreads();
    const unsigned int kmin = info[img] << 20;
    const float4* p4 = (const float4*)(obj + (size_t)img * A);
    const int nvec = A >> 2;
    for (int i = blockIdx.x * blockDim.x + threadIdx.x; i < nvec; i += blockDim.x * gridDim.x) {
        float4 v = p4[i];
        unsigned int k0 = fkey(v.x), k1 = fkey(v.y), k2 = fkey(v.z), k3 = fkey(v.w);
        unsigned int base = (unsigned int)(i << 2);
        if (k0 >= kmin) { unsigned int p = atomicAdd(&lcnt, 1u); if (p < BLK_CAND_CAP) loc[p] = ((unsigned long long)k0 << 32) | (0xFFFFFFFFu - base); }
        if (k1 >= kmin) { unsigned int p = atomicAdd(&lcnt, 1u); if (p < BLK_CAND_CAP) loc[p] = ((unsigned long long)k1 << 32) | (0xFFFFFFFFu - (base + 1u)); }
        if (k2 >= kmin) { unsigned int p = atomicAdd(&lcnt, 1u); if (p < BLK_CAND_CAP) loc[p] = ((unsigned long long)k2 << 32) | (0xFFFFFFFFu - (base + 2u)); }
        if (k3 >= kmin) { unsigned int p = atomicAdd(&lcnt, 1u); if (p < BLK_CAND_CAP) loc[p] = ((unsigned long long)k3 << 32) | (0xFFFFFFFFu - (base + 3u)); }
    }
    if (blockIdx.x == 0) {
        const float* p = obj + (size_t)img * A;
        for (int i = (nvec << 2) + threadIdx.x; i < A; i += blockDim.x) {
            unsigned int k = fkey(p[i]);
            if (k >= kmin) { unsigned int pp = atomicAdd(&lcnt, 1u); if (pp < BLK_CAND_CAP) loc[pp] = ((unsigned long long)k << 32) | (0xFFFFFFFFu - (unsigned int)i); }
        }
    }
    __syncthreads();
    unsigned int n = min(lcnt, (unsigned int)BLK_CAND_CAP);
    if (threadIdx.x == 0 && n) gbase = atomicAdd(ccnt + img * CNT_STRIDE, n);
    __syncthreads();
    unsigned long long* c = cand + (size_t)img * CAND_CAP;
    for (unsigned int i = threadIdx.x; i < n; i += blockDim.x) {
        unsigned int p = gbase + i;
        if (p < CAND_CAP) c[p] = loc[i];
    }
}

// per-image: bitonic sort candidates desc (key, then smaller idx first) -> top-2000 -> decode/clip/valid
__global__ __launch_bounds__(1024) void k_sortdecode(
    const float* __restrict__ obj, const float* __restrict__ deltas, const float* __restrict__ anchors,
    const unsigned long long* __restrict__ cand, const unsigned int* __restrict__ ccnt,
    float* __restrict__ boxes, float* __restrict__ scores, unsigned int* __restrict__ valid, int A) {
    __shared__ unsigned long long sb[CAND_CAP];   // 64 KB
    const int img = blockIdx.x;
    const int t = threadIdx.x;
    int n = (int)ccnt[img * CNT_STRIDE];
    if (n > CAND_CAP) n = CAND_CAP;
    int Ns = 2048;
    while (Ns < n) Ns <<= 1;
    const unsigned long long* c = cand + (size_t)img * CAND_CAP;
    for (int i = t; i < Ns; i += 1024) sb[i] = (i < n) ? c[i] : 0ull;
    __syncthreads();
    for (int k = 2; k <= Ns; k <<= 1) {
        for (int j = k >> 1; j > 0; j >>= 1) {
            for (int i = t; i < Ns; i += 1024) {
                int l = i ^ j;
                if (l > i) {
                    unsigned long long a = sb[i], b = sb[l];
                    bool sw = ((i & k) == 0) ? (a < b) : (a > b);   // overall descending
                    if (sw) { sb[i] = b; sb[l] = a; }
                }
            }
            __syncthreads();
        }
    }
    for (int e = t; e < PRE; e += 1024) {
        unsigned long long v = sb[e];
        unsigned int idx = 0xFFFFFFFFu - (unsigned int)(v & 0xFFFFFFFFull);
        float logit = obj[(size_t)img * A + idx];
        float4 d = ((const float4*)deltas)[(size_t)img * A + idx];
        float4 a = ((const float4*)anchors)[idx];
        float wa = a.z - a.x, ha = a.w - a.y;
        float cxa = a.x + 0.5f * wa, cya = a.y + 0.5f * ha;
        float dw = fminf(d.z, BBOX_CLIP_F), dh = fminf(d.w, BBOX_CLIP_F);
        float pcx = d.x * wa + cxa, pcy = d.y * ha + cya;
        float pw = expf(dw) * wa, ph = expf(dh) * ha;
        float x1 = fminf(fmaxf(pcx - 0.5f * pw, 0.0f), IMGW);
        float y1 = fminf(fmaxf(pcy - 0.5f * ph, 0.0f), IMGW);
        float x2 = fminf(fmaxf(pcx + 0.5f * pw, 0.0f), IMGW);
        float y2 = fminf(fmaxf(pcy + 0.5f * ph, 0.0f), IMGW);
        float sc = 1.0f / (1.0f + expf(-logit));
        unsigned int vd = (((x2 - x1) >= 1e-3f) && ((y2 - y1) >= 1e-3f) && (sc > 0.0f)) ? 1u : 0u;
        ((float4*)boxes)[(size_t)img * PRE + e] = make_float4(x1, y1, x2, y2);
        scores[img * PRE + e] = sc;
        valid[img * PRE + e] = vd;
    }
}

// sparse suppression pairs: emit (i<j) with IoU > 0.7 — LDS-staged, one global atomic per block
__global__ void k_pairs(const float* __restrict__ boxes, unsigned int* __restrict__ pairs,
                        unsigned int* __restrict__ pcnt) {
#pragma clang fp contract(off)
    __shared__ float bx1[PRE], by1[PRE], bx2[PRE], by2[PRE], bar[PRE];
    __shared__ unsigned int lp[BLK_PAIR_CAP];   // 8 KB
    __shared__ unsigned int lcnt, gbase;
    const int img = blockIdx.y;
    if (threadIdx.x == 0) lcnt = 0u;
    const float4* B = (const float4*)(boxes + (size_t)img * PRE * 4);
    for (int i = threadIdx.x; i < PRE; i += blockDim.x) {
        float4 b = B[i];
        bx1[i] = b.x; by1[i] = b.y; bx2[i] = b.z; by2[i] = b.w;
        bar[i] = (b.z - b.x) * (b.w - b.y);
    }
    __syncthreads();
    const int r0 = blockIdx.x * 63;
    const int r1 = min(r0 + 63, PRE);
    for (int i = r0; i < r1; ++i) {
        float x1 = bx1[i], y1 = by1[i], x2 = bx2[i], y2 = by2[i], ai = bar[i];
        for (int j = i + 1 + threadIdx.x; j < PRE; j += blockDim.x) {
            float xx1 = fmaxf(x1, bx1[j]);
            float yy1 = fmaxf(y1, by1[j]);
            float xx2 = fminf(x2, bx2[j]);
            float yy2 = fminf(y2, by2[j]);
            float iw = fmaxf(xx2 - xx1, 0.0f);
            float ih = fmaxf(yy2 - yy1, 0.0f);
            float inter = iw * ih;
            float iou = inter / (ai + bar[j] - inter + 1e-12f);
            if (iou > 0.7f) {
                unsigned int p = atomicAdd(&lcnt, 1u);
                if (p < BLK_PAIR_CAP) lp[p] = ((unsigned int)i << 11) | (unsigned int)j;
            }
        }
    }
    __syncthreads();
    unsigned int n = min(lcnt, (unsigned int)BLK_PAIR_CAP);
    if (threadIdx.x == 0 && n) gbase = atomicAdd(pcnt + img * CNT_STRIDE, n);
    __syncthreads();
    unsigned int* pp = pairs + (size_t)img * PAIR_CAP;
    for (unsigned int i = threadIdx.x; i < n; i += blockDim.x) {
        unsigned int p = gbase + i;
        if (p < PAIR_CAP) pp[p] = lp[i];
    }
}

// per-image: sort pairs by (i,j), serial greedy apply, prefix-scan keep, write [1000,5]
__global__ __launch_bounds__(1024) void k_final(
    const float* __restrict__ boxes, const float* __restrict__ scores, const unsigned int* __restrict__ valid,
    const unsigned int* __restrict__ pairs, const unsigned int* __restrict__ pcnt, float* __restrict__ out) {
    __shared__ unsigned int pb[PAIR_CAP];     // 48 KB
    __shared__ unsigned char keep[2048];
    __shared__ unsigned int incl[2048];
    const int img = blockIdx.x;
    const int t = threadIdx.x;
    int np = (int)pcnt[img * CNT_STRIDE];
    if (np > PAIR_CAP) np = PAIR_CAP;
    int Np = 2;
    while (Np < np) Np <<= 1;
    const unsigned int* ps = pairs + (size_t)img * PAIR_CAP;
    for (int i = t; i < Np; i += 1024) pb[i] = (i < np) ? ps[i] : 0xFFFFFFFFu;
    for (int i = t; i < 2048; i += 1024) keep[i] = (i < PRE) ? (unsigned char)valid[img * PRE + i] : 0;
    __syncthreads();
    for (int k = 2; k <= Np; k <<= 1) {
        for (int j = k >> 1; j > 0; j >>= 1) {
            for (int i = t; i < Np; i += 1024) {
                int l = i ^ j;
                if (l > i) {
                    unsigned int a = pb[i], b = pb[l];
                    bool sw = ((i & k) == 0) ? (a > b) : (a < b);   // ascending
                    if (sw) { pb[i] = b; pb[l] = a; }
                }
            }
            __syncthreads();
        }
    }
    if (t == 0) {
        // greedy NMS: pairs sorted by i ascending; keep[i] is final when its pairs are processed
        for (int p = 0; p < np; ++p) {
            unsigned int u = pb[p];
            unsigned int i = u >> 11, j = u & 2047u;
            if (keep[i]) keep[j] = 0;
        }
    }
    __syncthreads();
    const int i0 = t, i1 = t + 1024;
    incl[i0] = keep[i0]; incl[i1] = keep[i1];
    __syncthreads();
    for (int d = 1; d < 2048; d <<= 1) {
        unsigned int v0 = (i0 >= d) ? incl[i0 - d] : 0u;
        unsigned int v1 = (i1 >= d) ? incl[i1 - d] : 0u;
        __syncthreads();
        incl[i0] += v0; incl[i1] += v1;
        __syncthreads();
    }
    const unsigned int Nk = incl[2047];
    for (int i = t; i < PRE; i += 1024) {
        int slot = -1;
        float sc = 0.0f;
        if (keep[i]) {
            unsigned int r = incl[i] - 1u;
            if (r < (unsigned int)POST) { slot = (int)r; sc = scores[img * PRE + i]; }
        } else if (Nk < (unsigned int)POST) {
            unsigned int rnk = (unsigned int)i - incl[i];      // non-kept rank (ascending index)
            unsigned int s2 = Nk + rnk;
            if (s2 < (unsigned int)POST) { slot = (int)s2; sc = 0.0f; }
        }
        if (slot >= 0) {
            float4 b = ((const float4*)boxes)[(size_t)img * PRE + i];
            float* o = out + ((size_t)img * POST + slot) * 5;
            o[0] = b.x; o[1] = b.y; o[2] = b.z; o[3] = b.w; o[4] = sc;
        }
    }
}

extern "C" void kernel_launch(void* const* d_in, const int* in_sizes, int n_in,
                              void* d_out, int out_size, void* d_ws, size_t ws_size,
                              hipStream_t stream) {
    const float* obj = (const float*)d_in[0];
    const float* deltas = (const float*)d_in[1];
    const float* anchors = (const float*)d_in[2];
    float* out = (float*)d_out;
    const int A = in_sizes[0] / NIMG;

    char* ws = (char*)d_ws;
    unsigned int* hist = (unsigned int*)(ws + OFF_HIST);
    unsigned int* info = (unsigned int*)(ws + OFF_INFO);
    unsigned int* ccnt = (unsigned int*)(ws + OFF_CCNT);
    unsigned int* pcnt = (unsigned int*)(ws + OFF_PCNT);
    unsigned long long* cand = (unsigned long long*)(ws + OFF_CAND);
    float* boxes = (float*)(ws + OFF_BOX);
    float* scores = (float*)(ws + OFF_SCORE);
    unsigned int* valid = (unsigned int*)(ws + OFF_VALID);
    unsigned int* pairs = (unsigned int*)(ws + OFF_PAIRS);

    const int nzero = ZERO_BYTES / 4;
    k_zero<<<dim3((nzero + 255) / 256), dim3(256), 0, stream>>>((unsigned int*)ws, nzero);
    k_hist<<<dim3(64, NIMG), dim3(256), 0, stream>>>(obj, hist, A);
    k_scan<<<dim3(NIMG), dim3(256), 0, stream>>>(hist, info, PRE);
    k_compact<<<dim3(64, NIMG), dim3(256), 0, stream>>>(obj, info, cand, ccnt, A);
    k_sortdecode<<<dim3(NIMG), dim3(1024), 0, stream>>>(obj, deltas, anchors, cand, ccnt, boxes, scores, valid, A);
    k_pairs<<<dim3(32, NIMG), dim3(256), 0, stream>>>(boxes, pairs, pcnt);
    k_final<<<dim3(NIMG), dim3(1024), 0, stream>>>(boxes, scores, valid, pairs, pcnt, out);
}

// Round 3
// 319.326 us; speedup vs baseline: 1.9923x; 1.2081x over previous
//
#include <hip/hip_runtime.h>
#include <cstdint>

#define NIMG 8
#define PRE 2000
#define POST 1000
#define NBINS 4096
#define CAND_CAP 8192
#define BLK_CAND_CAP 2048
#define PAIR_CAP 12288
#define BLK_PAIR_CAP 1024
#define JT 256                                   // k_pairs tile edge
#define IMGW 800.0f
#define BBOX_CLIP_F 4.135166556742356f

// workspace layout (bytes)
#define OFF_HIST 0
#define OFF_INFO 131072                          // 8 u32 (+pad)
#define OFF_CCNT (OFF_INFO + 64)                 // 8 counters @ 128B stride
#define OFF_PCNT (OFF_CCNT + 1024)               // 8 counters @ 128B stride
#define ZERO_BYTES (OFF_PCNT + 1024)
#define OFF_CAND ZERO_BYTES                      // u64[8][8192] (sorted in place by k_sort4)
#define OFF_BOX  (OFF_CAND + NIMG*CAND_CAP*8)    // float[8][2000][4]
#define OFF_SCORE (OFF_BOX + NIMG*PRE*16)
#define OFF_VALID (OFF_SCORE + NIMG*PRE*4)
#define OFF_PAIRS (OFF_VALID + NIMG*PRE*4)       // u32[8][12288]

#define CNT_STRIDE 32                            // u32 units: 128 B between per-image counters

__device__ __forceinline__ unsigned int fkey(float f) {
    unsigned int b = __float_as_uint(f);
    return (b & 0x80000000u) ? ~b : (b | 0x80000000u);   // monotone float->uint
}
__device__ __forceinline__ float inv_fkey(unsigned int k) {
    unsigned int b = (k & 0x80000000u) ? (k ^ 0x80000000u) : ~k;
    return __uint_as_float(b);
}

__global__ void k_zero(unsigned int* __restrict__ p, int n) {
    int i = blockIdx.x * blockDim.x + threadIdx.x;
    if (i < n) p[i] = 0u;
}

__global__ void k_hist(const float* __restrict__ obj, unsigned int* __restrict__ hist, int A) {
    __shared__ unsigned int h[NBINS];
    const int img = blockIdx.y;
    for (int i = threadIdx.x; i < NBINS; i += blockDim.x) h[i] = 0u;
    __syncthreads();
    const float4* p4 = (const float4*)(obj + (size_t)img * A);
    const int nvec = A >> 2;
    for (int i = blockIdx.x * blockDim.x + threadIdx.x; i < nvec; i += blockDim.x * gridDim.x) {
        float4 v = p4[i];
        atomicAdd(&h[fkey(v.x) >> 20], 1u);
        atomicAdd(&h[fkey(v.y) >> 20], 1u);
        atomicAdd(&h[fkey(v.z) >> 20], 1u);
        atomicAdd(&h[fkey(v.w) >> 20], 1u);
    }
    if (blockIdx.x == 0) {
        const float* p = obj + (size_t)img * A;
        for (int i = (nvec << 2) + threadIdx.x; i < A; i += blockDim.x)
            atomicAdd(&h[fkey(p[i]) >> 20], 1u);
    }
    __syncthreads();
    for (int i = threadIdx.x; i < NBINS; i += blockDim.x)
        if (h[i]) atomicAdd(&hist[img * NBINS + i], h[i]);
}

// find largest bin b with count(bins >= b) >= K  (unique crossing)
__global__ void k_scan(const unsigned int* __restrict__ hist, unsigned int* __restrict__ info, int K) {
    __shared__ unsigned int seg[256];
    __shared__ unsigned int sufx[256];
    const int img = blockIdx.x;
    const int t = threadIdx.x;
    const unsigned int* h = hist + img * NBINS;
    unsigned int loc[16];
    unsigned int s = 0;
#pragma unroll
    for (int k = 0; k < 16; ++k) { loc[k] = h[t * 16 + k]; s += loc[k]; }
    seg[t] = s;
    __syncthreads();
    if (t == 0) {
        unsigned int r = 0;
        for (int i = 255; i >= 0; --i) { sufx[i] = r; r += seg[i]; }
    }
    __syncthreads();
    unsigned int run = sufx[t];
#pragma unroll
    for (int k = 15; k >= 0; --k) {
        unsigned int nrun = run + loc[k];
        if (run < (unsigned int)K && nrun >= (unsigned int)K)
            info[img] = (unsigned int)(t * 16 + k);
        run = nrun;
    }
}

// LDS-staged compaction: per-block shared buffer + ONE global atomic per block.
__global__ void k_compact(const float* __restrict__ obj, const unsigned int* __restrict__ info,
                          unsigned long long* __restrict__ cand, unsigned int* __restrict__ ccnt, int A) {
    __shared__ unsigned long long loc[BLK_CAND_CAP];   // 16 KB
    __shared__ unsigned int lcnt, gbase;
    const int img = blockIdx.y;
    if (threadIdx.x == 0) lcnt = 0u;
    __syncthreads();
    const unsigned int kmin = info[img] << 20;
    const float4* p4 = (const float4*)(obj + (size_t)img * A);
    const int nvec = A >> 2;
    for (int i = blockIdx.x * blockDim.x + threadIdx.x; i < nvec; i += blockDim.x * gridDim.x) {
        float4 v = p4[i];
        unsigned int k0 = fkey(v.x), k1 = fkey(v.y), k2 = fkey(v.z), k3 = fkey(v.w);
        unsigned int base = (unsigned int)(i << 2);
        if (k0 >= kmin) { unsigned int p = atomicAdd(&lcnt, 1u); if (p < BLK_CAND_CAP) loc[p] = ((unsigned long long)k0 << 32) | (0xFFFFFFFFu - base); }
        if (k1 >= kmin) { unsigned int p = atomicAdd(&lcnt, 1u); if (p < BLK_CAND_CAP) loc[p] = ((unsigned long long)k1 << 32) | (0xFFFFFFFFu - (base + 1u)); }
        if (k2 >= kmin) { unsigned int p = atomicAdd(&lcnt, 1u); if (p < BLK_CAND_CAP) loc[p] = ((unsigned long long)k2 << 32) | (0xFFFFFFFFu - (base + 2u)); }
        if (k3 >= kmin) { unsigned int p = atomicAdd(&lcnt, 1u); if (p < BLK_CAND_CAP) loc[p] = ((unsigned long long)k3 << 32) | (0xFFFFFFFFu - (base + 3u)); }
    }
    if (blockIdx.x == 0) {
        const float* p = obj + (size_t)img * A;
        for (int i = (nvec << 2) + threadIdx.x; i < A; i += blockDim.x) {
            unsigned int k = fkey(p[i]);
            if (k >= kmin) { unsigned int pp = atomicAdd(&lcnt, 1u); if (pp < BLK_CAND_CAP) loc[pp] = ((unsigned long long)k << 32) | (0xFFFFFFFFu - (unsigned int)i); }
        }
    }
    __syncthreads();
    unsigned int n = min(lcnt, (unsigned int)BLK_CAND_CAP);
    if (threadIdx.x == 0 && n) gbase = atomicAdd(ccnt + img * CNT_STRIDE, n);
    __syncthreads();
    unsigned long long* c = cand + (size_t)img * CAND_CAP;
    for (unsigned int i = threadIdx.x; i < n; i += blockDim.x) {
        unsigned int p = gbase + i;
        if (p < CAND_CAP) c[p] = loc[i];
    }
}

// sort each 2048-chunk of the candidate list descending, in place (32 independent blocks)
__global__ __launch_bounds__(1024) void k_sort4(unsigned long long* __restrict__ cand,
                                                const unsigned int* __restrict__ ccnt) {
    __shared__ unsigned long long sb[2048];   // 16 KB
    const int img = blockIdx.y;
    const int t = threadIdx.x;
    const int base = blockIdx.x * 2048;
    int n = (int)ccnt[img * CNT_STRIDE];
    if (n > CAND_CAP) n = CAND_CAP;
    unsigned long long* c = cand + (size_t)img * CAND_CAP;
    for (int i = t; i < 2048; i += 1024) {
        int g = base + i;
        sb[i] = (g < n) ? c[g] : 0ull;
    }
    __syncthreads();
    for (int k = 2; k <= 2048; k <<= 1) {
        for (int j = k >> 1; j > 0; j >>= 1) {
            for (int i = t; i < 2048; i += 1024) {
                int l = i ^ j;
                if (l > i) {
                    unsigned long long a = sb[i], b = sb[l];
                    bool sw = ((i & k) == 0) ? (a < b) : (a > b);   // overall descending
                    if (sw) { sb[i] = b; sb[l] = a; }
                }
            }
            __syncthreads();
        }
    }
    for (int i = t; i < 2048; i += 1024) c[base + i] = sb[i];
}

// merge 4 sorted chunks by exact global rank (keys unique); decode+clip ranks < PRE
__global__ __launch_bounds__(1024) void k_merge_decode(
    const float* __restrict__ deltas, const float* __restrict__ anchors,
    const unsigned long long* __restrict__ cand,
    float* __restrict__ boxes, float* __restrict__ scores, unsigned int* __restrict__ valid, int A) {
    __shared__ unsigned long long sb[CAND_CAP];   // 64 KB
    const int img = blockIdx.x;
    const int t = threadIdx.x;
    const unsigned long long* c = cand + (size_t)img * CAND_CAP;
    for (int i = t; i < CAND_CAP; i += 1024) sb[i] = c[i];
    __syncthreads();
    for (int e = t; e < CAND_CAP; e += 1024) {
        unsigned long long v = sb[e];
        if (v == 0ull) continue;                      // padding (real keys have key>=kmin>0)
        int rank = e & 2047;                          // position within own sorted chunk
        int myseg = e >> 11;
#pragma unroll
        for (int s = 0; s < 4; ++s) {
            if (s == myseg) continue;
            int lo = 0, hi = 2048;
            const unsigned long long* seg = sb + (s << 11);
            while (lo < hi) {                         // count elements > v (desc order)
                int mid = (lo + hi) >> 1;
                if (seg[mid] > v) lo = mid + 1; else hi = mid;
            }
            rank += lo;
        }
        if (rank >= PRE) continue;
        unsigned int idx = 0xFFFFFFFFu - (unsigned int)(v & 0xFFFFFFFFull);
        float logit = inv_fkey((unsigned int)(v >> 32));
        float4 d = ((const float4*)deltas)[(size_t)img * A + idx];
        float4 a = ((const float4*)anchors)[idx];
        float wa = a.z - a.x, ha = a.w - a.y;
        float cxa = a.x + 0.5f * wa, cya = a.y + 0.5f * ha;
        float dw = fminf(d.z, BBOX_CLIP_F), dh = fminf(d.w, BBOX_CLIP_F);
        float pcx = d.x * wa + cxa, pcy = d.y * ha + cya;
        float pw = expf(dw) * wa, ph = expf(dh) * ha;
        float x1 = fminf(fmaxf(pcx - 0.5f * pw, 0.0f), IMGW);
        float y1 = fminf(fmaxf(pcy - 0.5f * ph, 0.0f), IMGW);
        float x2 = fminf(fmaxf(pcx + 0.5f * pw, 0.0f), IMGW);
        float y2 = fminf(fmaxf(pcy + 0.5f * ph, 0.0f), IMGW);
        float sc = 1.0f / (1.0f + expf(-logit));
        unsigned int vd = (((x2 - x1) >= 1e-3f) && ((y2 - y1) >= 1e-3f) && (sc > 0.0f)) ? 1u : 0u;
        ((float4*)boxes)[(size_t)img * PRE + rank] = make_float4(x1, y1, x2, y2);
        scores[img * PRE + rank] = sc;
        valid[img * PRE + rank] = vd;
    }
}

// sparse suppression pairs: register-row x LDS-tile all-pairs, emit (i<j) with IoU > 0.7
__global__ void k_pairs(const float* __restrict__ boxes, unsigned int* __restrict__ pairs,
                        unsigned int* __restrict__ pcnt) {
#pragma clang fp contract(off)
    const int it = blockIdx.x >> 3;          // i-tile 0..7
    const int jc = blockIdx.x & 7;           // j-tile 0..7
    if (jc < it) return;                     // strictly-lower tiles have no i<j pairs
    __shared__ float4 jb[JT];                // 4 KB
    __shared__ float jar[JT];                // 1 KB
    __shared__ unsigned int lp[BLK_PAIR_CAP];// 4 KB
    __shared__ unsigned int lcnt, gbase;
    const int img = blockIdx.y;
    const int t = threadIdx.x;
    if (t == 0) lcnt = 0u;
    const float4* B = (const float4*)(boxes + (size_t)img * PRE * 4);
    const int j0 = jc * JT;
    const int jn = min(JT, PRE - j0);
    if (t < jn) {
        float4 b = B[j0 + t];
        jb[t] = b;
        jar[t] = (b.z - b.x) * (b.w - b.y);
    }
    const int i = it * JT + t;               // this thread's row (register-resident)
    const bool alive = (i < PRE);
    float x1 = 0, y1 = 0, x2 = 0, y2 = 0, ai = 0;
    if (alive) {
        float4 b = B[i];
        x1 = b.x; y1 = b.y; x2 = b.z; y2 = b.w;
        ai = (b.z - b.x) * (b.w - b.y);
    }
    __syncthreads();
    if (alive) {
#pragma unroll 4
        for (int jj = 0; jj < jn; ++jj) {    // uniform loop: broadcast LDS reads
            float4 bj = jb[jj];
            float aj = jar[jj];
            float xx1 = fmaxf(x1, bj.x);
            float yy1 = fmaxf(y1, bj.y);
            float xx2 = fminf(x2, bj.z);
            float yy2 = fminf(y2, bj.w);
            float iw = fmaxf(xx2 - xx1, 0.0f);
            float ih = fmaxf(yy2 - yy1, 0.0f);
            float inter = iw * ih;
            float iou = inter / (ai + aj - inter + 1e-12f);
            int j = j0 + jj;
            if (iou > 0.7f && j > i) {
                unsigned int p = atomicAdd(&lcnt, 1u);
                if (p < BLK_PAIR_CAP) lp[p] = ((unsigned int)i << 11) | (unsigned int)j;
            }
        }
    }
    __syncthreads();
    unsigned int n = min(lcnt, (unsigned int)BLK_PAIR_CAP);
    if (t == 0 && n) gbase = atomicAdd(pcnt + img * CNT_STRIDE, n);
    __syncthreads();
    unsigned int* pp = pairs + (size_t)img * PAIR_CAP;
    for (unsigned int q = t; q < n; q += blockDim.x) {
        unsigned int p = gbase + q;
        if (p < PAIR_CAP) pp[p] = lp[q];
    }
}

// per-image: sort pairs by (i,j), serial greedy apply, prefix-scan keep, write [1000,5]
__global__ __launch_bounds__(1024) void k_final(
    const float* __restrict__ boxes, const float* __restrict__ scores, const unsigned int* __restrict__ valid,
    const unsigned int* __restrict__ pairs, const unsigned int* __restrict__ pcnt, float* __restrict__ out) {
    __shared__ unsigned int pb[PAIR_CAP];     // 48 KB
    __shared__ unsigned char keep[2048];
    __shared__ unsigned int incl[2048];
    const int img = blockIdx.x;
    const int t = threadIdx.x;
    int np = (int)pcnt[img * CNT_STRIDE];
    if (np > PAIR_CAP) np = PAIR_CAP;
    int Np = 2;
    while (Np < np) Np <<= 1;
    const unsigned int* ps = pairs + (size_t)img * PAIR_CAP;
    for (int i = t; i < Np; i += 1024) pb[i] = (i < np) ? ps[i] : 0xFFFFFFFFu;
    for (int i = t; i < 2048; i += 1024) keep[i] = (i < PRE) ? (unsigned char)valid[img * PRE + i] : 0;
    __syncthreads();
    for (int k = 2; k <= Np; k <<= 1) {
        for (int j = k >> 1; j > 0; j >>= 1) {
            for (int i = t; i < Np; i += 1024) {
                int l = i ^ j;
                if (l > i) {
                    unsigned int a = pb[i], b = pb[l];
                    bool sw = ((i & k) == 0) ? (a > b) : (a < b);   // ascending
                    if (sw) { pb[i] = b; pb[l] = a; }
                }
            }
            __syncthreads();
        }
    }
    if (t == 0) {
        // greedy NMS: pairs sorted by i ascending; keep[i] is final when its pairs are processed
        for (int p = 0; p < np; ++p) {
            unsigned int u = pb[p];
            unsigned int i = u >> 11, j = u & 2047u;
            if (keep[i]) keep[j] = 0;
        }
    }
    __syncthreads();
    const int i0 = t, i1 = t + 1024;
    incl[i0] = keep[i0]; incl[i1] = keep[i1];
    __syncthreads();
    for (int d = 1; d < 2048; d <<= 1) {
        unsigned int v0 = (i0 >= d) ? incl[i0 - d] : 0u;
        unsigned int v1 = (i1 >= d) ? incl[i1 - d] : 0u;
        __syncthreads();
        incl[i0] += v0; incl[i1] += v1;
        __syncthreads();
    }
    const unsigned int Nk = incl[2047];
    for (int i = t; i < PRE; i += 1024) {
        int slot = -1;
        float sc = 0.0f;
        if (keep[i]) {
            unsigned int r = incl[i] - 1u;
            if (r < (unsigned int)POST) { slot = (int)r; sc = scores[img * PRE + i]; }
        } else if (Nk < (unsigned int)POST) {
            unsigned int rnk = (unsigned int)i - incl[i];      // non-kept rank (ascending index)
            unsigned int s2 = Nk + rnk;
            if (s2 < (unsigned int)POST) { slot = (int)s2; sc = 0.0f; }
        }
        if (slot >= 0) {
            float4 b = ((const float4*)boxes)[(size_t)img * PRE + i];
            float* o = out + ((size_t)img * POST + slot) * 5;
            o[0] = b.x; o[1] = b.y; o[2] = b.z; o[3] = b.w; o[4] = sc;
        }
    }
}

extern "C" void kernel_launch(void* const* d_in, const int* in_sizes, int n_in,
                              void* d_out, int out_size, void* d_ws, size_t ws_size,
                              hipStream_t stream) {
    const float* obj = (const float*)d_in[0];
    const float* deltas = (const float*)d_in[1];
    const float* anchors = (const float*)d_in[2];
    float* out = (float*)d_out;
    const int A = in_sizes[0] / NIMG;

    char* ws = (char*)d_ws;
    unsigned int* hist = (unsigned int*)(ws + OFF_HIST);
    unsigned int* info = (unsigned int*)(ws + OFF_INFO);
    unsigned int* ccnt = (unsigned int*)(ws + OFF_CCNT);
    unsigned int* pcnt = (unsigned int*)(ws + OFF_PCNT);
    unsigned long long* cand = (unsigned long long*)(ws + OFF_CAND);
    float* boxes = (float*)(ws + OFF_BOX);
    float* scores = (float*)(ws + OFF_SCORE);
    unsigned int* valid = (unsigned int*)(ws + OFF_VALID);
    unsigned int* pairs = (unsigned int*)(ws + OFF_PAIRS);

    const int nzero = ZERO_BYTES / 4;
    k_zero<<<dim3((nzero + 255) / 256), dim3(256), 0, stream>>>((unsigned int*)ws, nzero);
    k_hist<<<dim3(64, NIMG), dim3(256), 0, stream>>>(obj, hist, A);
    k_scan<<<dim3(NIMG), dim3(256), 0, stream>>>(hist, info, PRE);
    k_compact<<<dim3(64, NIMG), dim3(256), 0, stream>>>(obj, info, cand, ccnt, A);
    k_sort4<<<dim3(4, NIMG), dim3(1024), 0, stream>>>(cand, ccnt);
    k_merge_decode<<<dim3(NIMG), dim3(1024), 0, stream>>>(deltas, anchors, cand, boxes, scores, valid, A);
    k_pairs<<<dim3(64, NIMG), dim3(256), 0, stream>>>(boxes, pairs, pcnt);
    k_final<<<dim3(NIMG), dim3(1024), 0, stream>>>(boxes, scores, valid, pairs, pcnt, out);
}

// Round 4
// 303.854 us; speedup vs baseline: 2.0938x; 1.0509x over previous
//
#include <hip/hip_runtime.h>
#include <cstdint>

#define NIMG 8
#define PRE 2000
#define POST 1000
#define NBINS 4096
#define CAND_CAP 8192
#define BLK_CAND_CAP 2048
#define PAIR_CAP 12288
#define BLK_PAIR_CAP 1024
#define JT 256                                   // k_pairs tile edge
#define IMGW 800.0f
#define BBOX_CLIP_F 4.135166556742356f

// workspace layout (bytes)
#define OFF_HIST 0
#define OFF_INFO 131072                          // 8 u32 (+pad)
#define OFF_CCNT (OFF_INFO + 64)                 // 8 counters @ 128B stride
#define OFF_PCNT (OFF_CCNT + 1024)               // 8 counters @ 128B stride
#define ZERO_BYTES 131072                        // only the histogram needs pre-zero
#define OFF_CAND (OFF_PCNT + 1024)               // u64[8][8192] (sorted in place by k_sort4)
#define OFF_BOX  (OFF_CAND + NIMG*CAND_CAP*8)    // float[8][2000][4]
#define OFF_SCORE (OFF_BOX + NIMG*PRE*16)
#define OFF_VALID (OFF_SCORE + NIMG*PRE*4)
#define OFF_PAIRS (OFF_VALID + NIMG*PRE*4)       // u32[8][12288]

#define CNT_STRIDE 32                            // u32 units: 128 B between per-image counters

__device__ __forceinline__ unsigned int fkey(float f) {
    unsigned int b = __float_as_uint(f);
    return (b & 0x80000000u) ? ~b : (b | 0x80000000u);   // monotone float->uint
}
__device__ __forceinline__ float inv_fkey(unsigned int k) {
    unsigned int b = (k & 0x80000000u) ? (k ^ 0x80000000u) : ~k;
    return __uint_as_float(b);
}

__global__ void k_zero(unsigned int* __restrict__ p, int n) {
    int i = blockIdx.x * blockDim.x + threadIdx.x;
    if (i < n) p[i] = 0u;
}

__global__ void k_hist(const float* __restrict__ obj, unsigned int* __restrict__ hist, int A) {
    __shared__ unsigned int h[NBINS];
    const int img = blockIdx.y;
    for (int i = threadIdx.x; i < NBINS; i += blockDim.x) h[i] = 0u;
    __syncthreads();
    const float4* p4 = (const float4*)(obj + (size_t)img * A);
    const int nvec = A >> 2;
    for (int i = blockIdx.x * blockDim.x + threadIdx.x; i < nvec; i += blockDim.x * gridDim.x) {
        float4 v = p4[i];
        atomicAdd(&h[fkey(v.x) >> 20], 1u);
        atomicAdd(&h[fkey(v.y) >> 20], 1u);
        atomicAdd(&h[fkey(v.z) >> 20], 1u);
        atomicAdd(&h[fkey(v.w) >> 20], 1u);
    }
    if (blockIdx.x == 0) {
        const float* p = obj + (size_t)img * A;
        for (int i = (nvec << 2) + threadIdx.x; i < A; i += blockDim.x)
            atomicAdd(&h[fkey(p[i]) >> 20], 1u);
    }
    __syncthreads();
    for (int i = threadIdx.x; i < NBINS; i += blockDim.x)
        if (h[i]) atomicAdd(&hist[img * NBINS + i], h[i]);
}

// find largest bin b with count(bins >= b) >= K  (unique crossing); also zero per-image counters
__global__ void k_scan(const unsigned int* __restrict__ hist, unsigned int* __restrict__ info,
                       unsigned int* __restrict__ ccnt, unsigned int* __restrict__ pcnt, int K) {
    __shared__ unsigned int seg[256];
    __shared__ unsigned int sufx[256];
    const int img = blockIdx.x;
    const int t = threadIdx.x;
    if (t == 0) { ccnt[img * CNT_STRIDE] = 0u; pcnt[img * CNT_STRIDE] = 0u; }
    const unsigned int* h = hist + img * NBINS;
    unsigned int loc[16];
    unsigned int s = 0;
#pragma unroll
    for (int k = 0; k < 16; ++k) { loc[k] = h[t * 16 + k]; s += loc[k]; }
    seg[t] = s;
    __syncthreads();
    if (t == 0) {
        unsigned int r = 0;
        for (int i = 255; i >= 0; --i) { sufx[i] = r; r += seg[i]; }
    }
    __syncthreads();
    unsigned int run = sufx[t];
#pragma unroll
    for (int k = 15; k >= 0; --k) {
        unsigned int nrun = run + loc[k];
        if (run < (unsigned int)K && nrun >= (unsigned int)K)
            info[img] = (unsigned int)(t * 16 + k);
        run = nrun;
    }
}

// LDS-staged compaction: per-block shared buffer + ONE global atomic per block.
__global__ void k_compact(const float* __restrict__ obj, const unsigned int* __restrict__ info,
                          unsigned long long* __restrict__ cand, unsigned int* __restrict__ ccnt, int A) {
    __shared__ unsigned long long loc[BLK_CAND_CAP];   // 16 KB
    __shared__ unsigned int lcnt, gbase;
    const int img = blockIdx.y;
    if (threadIdx.x == 0) lcnt = 0u;
    __syncthreads();
    const unsigned int kmin = info[img] << 20;
    const float4* p4 = (const float4*)(obj + (size_t)img * A);
    const int nvec = A >> 2;
    for (int i = blockIdx.x * blockDim.x + threadIdx.x; i < nvec; i += blockDim.x * gridDim.x) {
        float4 v = p4[i];
        unsigned int k0 = fkey(v.x), k1 = fkey(v.y), k2 = fkey(v.z), k3 = fkey(v.w);
        unsigned int base = (unsigned int)(i << 2);
        if (k0 >= kmin) { unsigned int p = atomicAdd(&lcnt, 1u); if (p < BLK_CAND_CAP) loc[p] = ((unsigned long long)k0 << 32) | (0xFFFFFFFFu - base); }
        if (k1 >= kmin) { unsigned int p = atomicAdd(&lcnt, 1u); if (p < BLK_CAND_CAP) loc[p] = ((unsigned long long)k1 << 32) | (0xFFFFFFFFu - (base + 1u)); }
        if (k2 >= kmin) { unsigned int p = atomicAdd(&lcnt, 1u); if (p < BLK_CAND_CAP) loc[p] = ((unsigned long long)k2 << 32) | (0xFFFFFFFFu - (base + 2u)); }
        if (k3 >= kmin) { unsigned int p = atomicAdd(&lcnt, 1u); if (p < BLK_CAND_CAP) loc[p] = ((unsigned long long)k3 << 32) | (0xFFFFFFFFu - (base + 3u)); }
    }
    if (blockIdx.x == 0) {
        const float* p = obj + (size_t)img * A;
        for (int i = (nvec << 2) + threadIdx.x; i < A; i += blockDim.x) {
            unsigned int k = fkey(p[i]);
            if (k >= kmin) { unsigned int pp = atomicAdd(&lcnt, 1u); if (pp < BLK_CAND_CAP) loc[pp] = ((unsigned long long)k << 32) | (0xFFFFFFFFu - (unsigned int)i); }
        }
    }
    __syncthreads();
    unsigned int n = min(lcnt, (unsigned int)BLK_CAND_CAP);
    if (threadIdx.x == 0 && n) gbase = atomicAdd(ccnt + img * CNT_STRIDE, n);
    __syncthreads();
    unsigned long long* c = cand + (size_t)img * CAND_CAP;
    for (unsigned int i = threadIdx.x; i < n; i += blockDim.x) {
        unsigned int p = gbase + i;
        if (p < CAND_CAP) c[p] = loc[i];
    }
}

// sort each 2048-chunk of the candidate list descending, in place (32 independent blocks)
__global__ __launch_bounds__(1024) void k_sort4(unsigned long long* __restrict__ cand,
                                                const unsigned int* __restrict__ ccnt) {
    __shared__ unsigned long long sb[2048];   // 16 KB
    const int img = blockIdx.y;
    const int t = threadIdx.x;
    const int base = blockIdx.x * 2048;
    int n = (int)ccnt[img * CNT_STRIDE];
    if (n > CAND_CAP) n = CAND_CAP;
    unsigned long long* c = cand + (size_t)img * CAND_CAP;
    for (int i = t; i < 2048; i += 1024) {
        int g = base + i;
        sb[i] = (g < n) ? c[g] : 0ull;
    }
    __syncthreads();
    for (int k = 2; k <= 2048; k <<= 1) {
        for (int j = k >> 1; j > 0; j >>= 1) {
            for (int i = t; i < 2048; i += 1024) {
                int l = i ^ j;
                if (l > i) {
                    unsigned long long a = sb[i], b = sb[l];
                    bool sw = ((i & k) == 0) ? (a < b) : (a > b);   // overall descending
                    if (sw) { sb[i] = b; sb[l] = a; }
                }
            }
            __syncthreads();
        }
    }
    for (int i = t; i < 2048; i += 1024) c[base + i] = sb[i];
}

// merge 4 sorted chunks by exact global rank (keys unique); decode+clip ranks < PRE.
// 4 blocks per image: each block ranks its own chunk against the other three.
__global__ __launch_bounds__(1024) void k_merge_decode(
    const float* __restrict__ deltas, const float* __restrict__ anchors,
    const unsigned long long* __restrict__ cand,
    float* __restrict__ boxes, float* __restrict__ scores, unsigned int* __restrict__ valid, int A) {
    __shared__ unsigned long long sb[CAND_CAP];   // 64 KB
    const int img = blockIdx.y;
    const int myseg = blockIdx.x;                 // 0..3
    const int t = threadIdx.x;
    const unsigned long long* c = cand + (size_t)img * CAND_CAP;
    for (int i = t; i < CAND_CAP; i += 1024) sb[i] = c[i];
    __syncthreads();
    for (int e2 = t; e2 < 2048; e2 += 1024) {
        const int e = (myseg << 11) + e2;
        unsigned long long v = sb[e];
        if (v == 0ull) continue;                  // padding (real keys have key>=kmin>0)
        int rank = e2;                            // position within own sorted chunk
#pragma unroll
        for (int s = 0; s < 4; ++s) {
            if (s == myseg) continue;
            int lo = 0, hi = 2048;
            const unsigned long long* seg = sb + (s << 11);
            while (lo < hi) {                     // count elements > v (desc order)
                int mid = (lo + hi) >> 1;
                if (seg[mid] > v) lo = mid + 1; else hi = mid;
            }
            rank += lo;
        }
        if (rank >= PRE) continue;
        unsigned int idx = 0xFFFFFFFFu - (unsigned int)(v & 0xFFFFFFFFull);
        float logit = inv_fkey((unsigned int)(v >> 32));
        float4 d = ((const float4*)deltas)[(size_t)img * A + idx];
        float4 a = ((const float4*)anchors)[idx];
        float wa = a.z - a.x, ha = a.w - a.y;
        float cxa = a.x + 0.5f * wa, cya = a.y + 0.5f * ha;
        float dw = fminf(d.z, BBOX_CLIP_F), dh = fminf(d.w, BBOX_CLIP_F);
        float pcx = d.x * wa + cxa, pcy = d.y * ha + cya;
        float pw = expf(dw) * wa, ph = expf(dh) * ha;
        float x1 = fminf(fmaxf(pcx - 0.5f * pw, 0.0f), IMGW);
        float y1 = fminf(fmaxf(pcy - 0.5f * ph, 0.0f), IMGW);
        float x2 = fminf(fmaxf(pcx + 0.5f * pw, 0.0f), IMGW);
        float y2 = fminf(fmaxf(pcy + 0.5f * ph, 0.0f), IMGW);
        float sc = 1.0f / (1.0f + expf(-logit));
        unsigned int vd = (((x2 - x1) >= 1e-3f) && ((y2 - y1) >= 1e-3f) && (sc > 0.0f)) ? 1u : 0u;
        ((float4*)boxes)[(size_t)img * PRE + rank] = make_float4(x1, y1, x2, y2);
        scores[img * PRE + rank] = sc;
        valid[img * PRE + rank] = vd;
    }
}

// sparse suppression pairs: register-row x LDS-tile all-pairs, emit (i<j) with IoU > 0.7
__global__ void k_pairs(const float* __restrict__ boxes, unsigned int* __restrict__ pairs,
                        unsigned int* __restrict__ pcnt) {
#pragma clang fp contract(off)
    const int it = blockIdx.x >> 3;          // i-tile 0..7
    const int jc = blockIdx.x & 7;           // j-tile 0..7
    if (jc < it) return;                     // strictly-lower tiles have no i<j pairs
    __shared__ float4 jb[JT];                // 4 KB
    __shared__ float jar[JT];                // 1 KB
    __shared__ unsigned int lp[BLK_PAIR_CAP];// 4 KB
    __shared__ unsigned int lcnt, gbase;
    const int img = blockIdx.y;
    const int t = threadIdx.x;
    if (t == 0) lcnt = 0u;
    const float4* B = (const float4*)(boxes + (size_t)img * PRE * 4);
    const int j0 = jc * JT;
    const int jn = min(JT, PRE - j0);
    if (t < jn) {
        float4 b = B[j0 + t];
        jb[t] = b;
        jar[t] = (b.z - b.x) * (b.w - b.y);
    }
    const int i = it * JT + t;               // this thread's row (register-resident)
    const bool alive = (i < PRE);
    float x1 = 0, y1 = 0, x2 = 0, y2 = 0, ai = 0;
    if (alive) {
        float4 b = B[i];
        x1 = b.x; y1 = b.y; x2 = b.z; y2 = b.w;
        ai = (b.z - b.x) * (b.w - b.y);
    }
    __syncthreads();
    if (alive) {
#pragma unroll 4
        for (int jj = 0; jj < jn; ++jj) {    // uniform loop: broadcast LDS reads
            float4 bj = jb[jj];
            float aj = jar[jj];
            float xx1 = fmaxf(x1, bj.x);
            float yy1 = fmaxf(y1, bj.y);
            float xx2 = fminf(x2, bj.z);
            float yy2 = fminf(y2, bj.w);
            float iw = fmaxf(xx2 - xx1, 0.0f);
            float ih = fmaxf(yy2 - yy1, 0.0f);
            float inter = iw * ih;
            float iou = inter / (ai + aj - inter + 1e-12f);
            int j = j0 + jj;
            if (iou > 0.7f && j > i) {
                unsigned int p = atomicAdd(&lcnt, 1u);
                if (p < BLK_PAIR_CAP) lp[p] = ((unsigned int)i << 11) | (unsigned int)j;
            }
        }
    }
    __syncthreads();
    unsigned int n = min(lcnt, (unsigned int)BLK_PAIR_CAP);
    if (t == 0 && n) gbase = atomicAdd(pcnt + img * CNT_STRIDE, n);
    __syncthreads();
    unsigned int* pp = pairs + (size_t)img * PAIR_CAP;
    for (unsigned int q = t; q < n; q += blockDim.x) {
        unsigned int p = gbase + q;
        if (p < PAIR_CAP) pp[p] = lp[q];
    }
}

// per-image: FIXPOINT greedy NMS (order-free, no pair sort), prefix-scan, write [1000,5].
// alive_{k+1}[j] = valid[j] && !exists edge (i,j) with alive_k[i]; unique fixpoint == greedy.
__global__ __launch_bounds__(1024) void k_final(
    const float* __restrict__ boxes, const float* __restrict__ scores, const unsigned int* __restrict__ valid,
    const unsigned int* __restrict__ pairs, const unsigned int* __restrict__ pcnt, float* __restrict__ out) {
    __shared__ unsigned int pb[PAIR_CAP];     // 48 KB
    __shared__ unsigned char vld[2048];
    __shared__ unsigned char alive[2048];
    __shared__ unsigned char kill[2048];
    __shared__ unsigned int incl[2048];
    __shared__ int changed;
    const int img = blockIdx.x;
    const int t = threadIdx.x;
    int np = (int)pcnt[img * CNT_STRIDE];
    if (np > PAIR_CAP) np = PAIR_CAP;
    const unsigned int* ps = pairs + (size_t)img * PAIR_CAP;
    for (int i = t; i < np; i += 1024) pb[i] = ps[i];
    for (int i = t; i < 2048; i += 1024) {
        unsigned char v = (i < PRE) ? (unsigned char)valid[img * PRE + i] : 0;
        vld[i] = v;
        alive[i] = v;
    }
    __syncthreads();
    for (int iter = 0; iter < 2048; ++iter) {
        if (t == 0) changed = 0;
        for (int i = t; i < 2048; i += 1024) kill[i] = 0;
        __syncthreads();
        for (int e = t; e < np; e += 1024) {
            unsigned int u = pb[e];
            unsigned int i = u >> 11, j = u & 2047u;
            if (alive[i]) kill[j] = 1;             // benign same-value races
        }
        __syncthreads();
        for (int i = t; i < 2048; i += 1024) {
            unsigned char na = (vld[i] && !kill[i]) ? 1 : 0;
            if (na != alive[i]) { alive[i] = na; changed = 1; }
        }
        __syncthreads();
        bool done = (changed == 0);
        __syncthreads();                           // protect 'changed' read vs next reset
        if (done) break;
    }
    const int i0 = t, i1 = t + 1024;
    incl[i0] = alive[i0]; incl[i1] = alive[i1];
    __syncthreads();
    for (int d = 1; d < 2048; d <<= 1) {
        unsigned int v0 = (i0 >= d) ? incl[i0 - d] : 0u;
        unsigned int v1 = (i1 >= d) ? incl[i1 - d] : 0u;
        __syncthreads();
        incl[i0] += v0; incl[i1] += v1;
        __syncthreads();
    }
    const unsigned int Nk = incl[2047];
    for (int i = t; i < PRE; i += 1024) {
        int slot = -1;
        float sc = 0.0f;
        if (alive[i]) {
            unsigned int r = incl[i] - 1u;
            if (r < (unsigned int)POST) { slot = (int)r; sc = scores[img * PRE + i]; }
        } else if (Nk < (unsigned int)POST) {
            unsigned int rnk = (unsigned int)i - incl[i];      // non-kept rank (ascending index)
            unsigned int s2 = Nk + rnk;
            if (s2 < (unsigned int)POST) { slot = (int)s2; sc = 0.0f; }
        }
        if (slot >= 0) {
            float4 b = ((const float4*)boxes)[(size_t)img * PRE + i];
            float* o = out + ((size_t)img * POST + slot) * 5;
            o[0] = b.x; o[1] = b.y; o[2] = b.z; o[3] = b.w; o[4] = sc;
        }
    }
}

extern "C" void kernel_launch(void* const* d_in, const int* in_sizes, int n_in,
                              void* d_out, int out_size, void* d_ws, size_t ws_size,
                              hipStream_t stream) {
    const float* obj = (const float*)d_in[0];
    const float* deltas = (const float*)d_in[1];
    const float* anchors = (const float*)d_in[2];
    float* out = (float*)d_out;
    const int A = in_sizes[0] / NIMG;

    char* ws = (char*)d_ws;
    unsigned int* hist = (unsigned int*)(ws + OFF_HIST);
    unsigned int* info = (unsigned int*)(ws + OFF_INFO);
    unsigned int* ccnt = (unsigned int*)(ws + OFF_CCNT);
    unsigned int* pcnt = (unsigned int*)(ws + OFF_PCNT);
    unsigned long long* cand = (unsigned long long*)(ws + OFF_CAND);
    float* boxes = (float*)(ws + OFF_BOX);
    float* scores = (float*)(ws + OFF_SCORE);
    unsigned int* valid = (unsigned int*)(ws + OFF_VALID);
    unsigned int* pairs = (unsigned int*)(ws + OFF_PAIRS);

    const int nzero = ZERO_BYTES / 4;
    k_zero<<<dim3((nzero + 255) / 256), dim3(256), 0, stream>>>((unsigned int*)ws, nzero);
    k_hist<<<dim3(32, NIMG), dim3(256), 0, stream>>>(obj, hist, A);
    k_scan<<<dim3(NIMG), dim3(256), 0, stream>>>(hist, info, ccnt, pcnt, PRE);
    k_compact<<<dim3(64, NIMG), dim3(256), 0, stream>>>(obj, info, cand, ccnt, A);
    k_sort4<<<dim3(4, NIMG), dim3(1024), 0, stream>>>(cand, ccnt);
    k_merge_decode<<<dim3(4, NIMG), dim3(1024), 0, stream>>>(deltas, anchors, cand, boxes, scores, valid, A);
    k_pairs<<<dim3(64, NIMG), dim3(256), 0, stream>>>(boxes, pairs, pcnt);
    k_final<<<dim3(NIMG), dim3(1024), 0, stream>>>(boxes, scores, valid, pairs, pcnt, out);
}

// Round 5
// 300.424 us; speedup vs baseline: 2.1177x; 1.0114x over previous
//
#include <hip/hip_runtime.h>
#include <cstdint>

#define NIMG 8
#define PRE 2000
#define POST 1000
#define NCH 64                    // candidate chunks per image (one per compact block)
#define CH_CAP 256                // entries per chunk
#define CAND_TOT (NCH*CH_CAP)     // 16384 slots per image
#define NSORT 4                   // sorter blocks per image
#define SEG 2048                  // sorted segment length
#define CAND_MAX (NSORT*SEG)      // 8192 candidates usable
#define NPB 64                    // pair-tile blocks per image
#define PB_CAP 1024               // pairs per tile block
#define PAIR_CAP 12288            // k_final LDS pair cap
#define JT 256                    // pair tile edge
#define IMGW 800.0f
#define BBOX_CLIP_F 4.135166556742356f
// fkey(2.5f): fast-path static threshold. Top-2000-of-1M N(0,1) cutoff is ~2.878+-0.007;
// count(logit>=2.5) ~ 6210+-79 per image -> >=PRE and <=CAND_MAX with >20 sigma margin.
// k_fallback rebuilds exactly (histogram) if this ever fails.
#define STATIC_KMIN 0xC0200000u

// workspace layout (bytes) -- no pre-zeroing needed anywhere
#define OFF_BCNT  0
#define OFF_BPCNT (OFF_BCNT + NIMG*NCH*4)
#define OFF_CAND  (OFF_BPCNT + NIMG*NPB*4)
#define OFF_SRT   (OFF_CAND + NIMG*CAND_TOT*8)
#define OFF_BOX   (OFF_SRT + NIMG*CAND_MAX*8)
#define OFF_SCORE (OFF_BOX + NIMG*PRE*16)
#define OFF_VALID (OFF_SCORE + NIMG*PRE*4)
#define OFF_PAIRS (OFF_VALID + NIMG*PRE*4)

__device__ __forceinline__ unsigned int fkey(float f) {
    unsigned int b = __float_as_uint(f);
    return (b & 0x80000000u) ? ~b : (b | 0x80000000u);   // monotone float->uint
}
__device__ __forceinline__ float inv_fkey(unsigned int k) {
    unsigned int b = (k & 0x80000000u) ? (k ^ 0x80000000u) : ~k;
    return __uint_as_float(b);
}

// single 32MB pass: static-threshold compact into per-block private chunks (no global atomics)
__global__ void k_compact(const float* __restrict__ obj,
                          unsigned long long* __restrict__ cand,
                          unsigned int* __restrict__ bcnt, int A) {
    __shared__ unsigned long long loc[CH_CAP];
    __shared__ unsigned int lcnt;
    const int img = blockIdx.y;
    const int b = blockIdx.x;
    const int t = threadIdx.x;
    if (t == 0) lcnt = 0u;
    __syncthreads();
    const float4* p4 = (const float4*)(obj + (size_t)img * A);
    const int nvec = A >> 2;
    for (int i = b * 256 + t; i < nvec; i += NCH * 256) {
        float4 v = p4[i];
        unsigned int k0 = fkey(v.x), k1 = fkey(v.y), k2 = fkey(v.z), k3 = fkey(v.w);
        unsigned int base = (unsigned int)(i << 2);
        if (k0 >= STATIC_KMIN) { unsigned int p = atomicAdd(&lcnt, 1u); if (p < CH_CAP) loc[p] = ((unsigned long long)k0 << 32) | (0xFFFFFFFFu - base); }
        if (k1 >= STATIC_KMIN) { unsigned int p = atomicAdd(&lcnt, 1u); if (p < CH_CAP) loc[p] = ((unsigned long long)k1 << 32) | (0xFFFFFFFFu - (base + 1u)); }
        if (k2 >= STATIC_KMIN) { unsigned int p = atomicAdd(&lcnt, 1u); if (p < CH_CAP) loc[p] = ((unsigned long long)k2 << 32) | (0xFFFFFFFFu - (base + 2u)); }
        if (k3 >= STATIC_KMIN) { unsigned int p = atomicAdd(&lcnt, 1u); if (p < CH_CAP) loc[p] = ((unsigned long long)k3 << 32) | (0xFFFFFFFFu - (base + 3u)); }
    }
    if (b == 0) {
        const float* p = obj + (size_t)img * A;
        for (int i = (nvec << 2) + t; i < A; i += 256) {
            unsigned int k = fkey(p[i]);
            if (k >= STATIC_KMIN) { unsigned int q = atomicAdd(&lcnt, 1u); if (q < CH_CAP) loc[q] = ((unsigned long long)k << 32) | (0xFFFFFFFFu - (unsigned int)i); }
        }
    }
    __syncthreads();
    if (t == 0) bcnt[img * NCH + b] = lcnt;          // raw count (overflow detectable)
    unsigned int n = min(lcnt, (unsigned int)CH_CAP);
    unsigned long long* dst = cand + (size_t)img * CAND_TOT + (size_t)b * CH_CAP;
    for (unsigned int i = t; i < n; i += 256) dst[i] = loc[i];
}

// exact rebuild if the static threshold failed (normally early-exits in ~2us)
__global__ __launch_bounds__(1024) void k_fallback(const float* __restrict__ obj,
                                                   unsigned long long* __restrict__ cand,
                                                   unsigned int* __restrict__ bcnt, int A) {
    __shared__ unsigned int h[4096];
    __shared__ unsigned int cnts[NCH];
    __shared__ int need_s;
    __shared__ unsigned int kth_s, c2;
    const int img = blockIdx.x;
    const int t = threadIdx.x;
    if (t < NCH) cnts[t] = bcnt[img * NCH + t];
    __syncthreads();
    if (t == 0) {
        unsigned int tot = 0; int bad = 0;
        for (int c = 0; c < NCH; ++c) { unsigned int r = cnts[c]; if (r > CH_CAP) bad = 1; tot += min(r, (unsigned int)CH_CAP); }
        for (int g = 0; g < NSORT; ++g) {
            unsigned int s = 0;
            for (int c = 0; c < NCH / NSORT; ++c) s += min(cnts[g * (NCH / NSORT) + c], (unsigned int)CH_CAP);
            if (s > SEG) bad = 1;
        }
        if (tot < PRE) bad = 1;
        need_s = bad;
    }
    __syncthreads();
    if (!need_s) return;
    for (int i = t; i < 4096; i += 1024) h[i] = 0u;
    __syncthreads();
    const float* p = obj + (size_t)img * A;
    for (int i = t; i < A; i += 1024) atomicAdd(&h[fkey(p[i]) >> 20], 1u);
    __syncthreads();
    if (t == 0) {
        unsigned int run = 0, kb = 0;
        for (int b = 4095; b >= 0; --b) { run += h[b]; if (run >= (unsigned int)PRE) { kb = (unsigned int)b; break; } }
        kth_s = kb << 20; c2 = 0u;
    }
    __syncthreads();
    for (int i = t; i < A; i += 1024) {
        unsigned int k = fkey(p[i]);
        if (k >= kth_s) {
            unsigned int q = atomicAdd(&c2, 1u);
            if (q < CAND_MAX)   // round-robin chunk mapping keeps every sorter group <= SEG
                cand[(size_t)img * CAND_TOT + (size_t)(q & (NCH - 1)) * CH_CAP + (q >> 6)] =
                    ((unsigned long long)k << 32) | (0xFFFFFFFFu - (unsigned int)i);
        }
    }
    __syncthreads();
    unsigned int tot = min(c2, (unsigned int)CAND_MAX);
    if (t < NCH) bcnt[img * NCH + t] = (tot + (NCH - 1) - t) >> 6;
}

// gather 16 chunks -> bitonic sort 2048 desc -> sorted segment
__global__ __launch_bounds__(1024) void k_sort(const unsigned long long* __restrict__ cand,
                                               const unsigned int* __restrict__ bcnt,
                                               unsigned long long* __restrict__ srt) {
    __shared__ unsigned long long sb[SEG];   // 16 KB
    __shared__ unsigned int pref[17];
    const int img = blockIdx.y;
    const int s = blockIdx.x;
    const int t = threadIdx.x;
    if (t == 0) {
        unsigned int o = 0; pref[0] = 0;
        for (int c = 0; c < 16; ++c) {
            unsigned int n = min(bcnt[img * NCH + s * 16 + c], (unsigned int)CH_CAP);
            o += n; if (o > (unsigned int)SEG) o = SEG;
            pref[c + 1] = o;
        }
    }
    for (int i = t; i < SEG; i += 1024) sb[i] = 0ull;
    __syncthreads();
    for (int c = 0; c < 16; ++c) {
        unsigned int b0 = pref[c], n = pref[c + 1] - pref[c];
        const unsigned long long* src = cand + (size_t)img * CAND_TOT + (size_t)(s * 16 + c) * CH_CAP;
        for (unsigned int i = t; i < n; i += 1024) sb[b0 + i] = src[i];
    }
    __syncthreads();
    for (int k = 2; k <= SEG; k <<= 1) {
        for (int j = k >> 1; j > 0; j >>= 1) {
            for (int i = t; i < SEG; i += 1024) {
                int l = i ^ j;
                if (l > i) {
                    unsigned long long a = sb[i], b = sb[l];
                    bool sw = ((i & k) == 0) ? (a < b) : (a > b);   // overall descending
                    if (sw) { sb[i] = b; sb[l] = a; }
                }
            }
            __syncthreads();
        }
    }
    unsigned long long* dst = srt + (size_t)img * CAND_MAX + (size_t)s * SEG;
    for (int i = t; i < SEG; i += 1024) dst[i] = sb[i];
}

// exact global rank via binary search vs the other 3 segments; decode+clip ranks < PRE
__global__ __launch_bounds__(1024) void k_merge_decode(
    const float* __restrict__ deltas, const float* __restrict__ anchors,
    const unsigned long long* __restrict__ srt,
    float* __restrict__ boxes, float* __restrict__ scores, unsigned int* __restrict__ valid, int A) {
    __shared__ unsigned long long sb[CAND_MAX];   // 64 KB
    const int img = blockIdx.y;
    const int myseg = blockIdx.x;                 // 0..3
    const int t = threadIdx.x;
    const unsigned long long* c = srt + (size_t)img * CAND_MAX;
    for (int i = t; i < CAND_MAX; i += 1024) sb[i] = c[i];
    __syncthreads();
    for (int e2 = t; e2 < SEG; e2 += 1024) {
        const int e = (myseg << 11) + e2;
        unsigned long long v = sb[e];
        if (v == 0ull) continue;                  // padding
        int rank = e2;
#pragma unroll
        for (int s = 0; s < 4; ++s) {
            if (s == myseg) continue;
            int lo = 0, hi = SEG;
            const unsigned long long* seg = sb + (s << 11);
            while (lo < hi) {                     // count elements > v (desc order)
                int mid = (lo + hi) >> 1;
                if (seg[mid] > v) lo = mid + 1; else hi = mid;
            }
            rank += lo;
        }
        if (rank >= PRE) continue;
        unsigned int idx = 0xFFFFFFFFu - (unsigned int)(v & 0xFFFFFFFFull);
        float logit = inv_fkey((unsigned int)(v >> 32));
        float4 d = ((const float4*)deltas)[(size_t)img * A + idx];
        float4 a = ((const float4*)anchors)[idx];
        float wa = a.z - a.x, ha = a.w - a.y;
        float cxa = a.x + 0.5f * wa, cya = a.y + 0.5f * ha;
        float dw = fminf(d.z, BBOX_CLIP_F), dh = fminf(d.w, BBOX_CLIP_F);
        float pcx = d.x * wa + cxa, pcy = d.y * ha + cya;
        float pw = expf(dw) * wa, ph = expf(dh) * ha;
        float x1 = fminf(fmaxf(pcx - 0.5f * pw, 0.0f), IMGW);
        float y1 = fminf(fmaxf(pcy - 0.5f * ph, 0.0f), IMGW);
        float x2 = fminf(fmaxf(pcx + 0.5f * pw, 0.0f), IMGW);
        float y2 = fminf(fmaxf(pcy + 0.5f * ph, 0.0f), IMGW);
        float sc = 1.0f / (1.0f + expf(-logit));
        unsigned int vd = (((x2 - x1) >= 1e-3f) && ((y2 - y1) >= 1e-3f) && (sc > 0.0f)) ? 1u : 0u;
        ((float4*)boxes)[(size_t)img * PRE + rank] = make_float4(x1, y1, x2, y2);
        scores[img * PRE + rank] = sc;
        valid[img * PRE + rank] = vd;
    }
}

// sparse suppression pairs (i<j, IoU>0.7): register-row x LDS-tile, per-block private region
__global__ void k_pairs(const float* __restrict__ boxes, unsigned int* __restrict__ pairs,
                        unsigned int* __restrict__ bpcnt) {
#pragma clang fp contract(off)
    const int img = blockIdx.y;
    const int bid = blockIdx.x;
    const int it = bid >> 3;
    const int jc = bid & 7;
    const int t = threadIdx.x;
    if (jc < it) { if (t == 0) bpcnt[img * NPB + bid] = 0u; return; }
    __shared__ float4 jb[JT];
    __shared__ float jar[JT];
    __shared__ unsigned int lp[PB_CAP];      // 4 KB
    __shared__ unsigned int lcnt;
    if (t == 0) lcnt = 0u;
    const float4* B = (const float4*)(boxes + (size_t)img * PRE * 4);
    const int j0 = jc * JT;
    const int jn = min(JT, PRE - j0);
    if (t < jn) {
        float4 b = B[j0 + t];
        jb[t] = b;
        jar[t] = (b.z - b.x) * (b.w - b.y);
    }
    const int i = it * JT + t;
    const bool row_ok = (i < PRE);
    float x1 = 0, y1 = 0, x2 = 0, y2 = 0, ai = 0;
    if (row_ok) {
        float4 b = B[i];
        x1 = b.x; y1 = b.y; x2 = b.z; y2 = b.w;
        ai = (b.z - b.x) * (b.w - b.y);
    }
    __syncthreads();
    if (row_ok) {
#pragma unroll 4
        for (int jj = 0; jj < jn; ++jj) {
            float4 bj = jb[jj];
            float aj = jar[jj];
            float xx1 = fmaxf(x1, bj.x);
            float yy1 = fmaxf(y1, bj.y);
            float xx2 = fminf(x2, bj.z);
            float yy2 = fminf(y2, bj.w);
            float iw = fmaxf(xx2 - xx1, 0.0f);
            float ih = fmaxf(yy2 - yy1, 0.0f);
            float inter = iw * ih;
            float iou = inter / (ai + aj - inter + 1e-12f);
            int j = j0 + jj;
            if (iou > 0.7f && j > i) {
                unsigned int p = atomicAdd(&lcnt, 1u);
                if (p < PB_CAP) lp[p] = ((unsigned int)i << 11) | (unsigned int)j;
            }
        }
    }
    __syncthreads();
    unsigned int n = min(lcnt, (unsigned int)PB_CAP);
    if (t == 0) bpcnt[img * NPB + bid] = n;
    unsigned int* dst = pairs + ((size_t)img * NPB + bid) * PB_CAP;
    for (unsigned int q = t; q < n; q += blockDim.x) dst[q] = lp[q];
}

// fixpoint greedy NMS (order-free), prefix-scan, write [1000,5]
__global__ __launch_bounds__(1024) void k_final(
    const float* __restrict__ boxes, const float* __restrict__ scores, const unsigned int* __restrict__ valid,
    const unsigned int* __restrict__ pairs, const unsigned int* __restrict__ bpcnt, float* __restrict__ out) {
    __shared__ unsigned int pb[PAIR_CAP];     // 48 KB
    __shared__ unsigned int bp[NPB];
    __shared__ unsigned int ofs[NPB + 1];
    __shared__ unsigned char vld[2048];
    __shared__ unsigned char alive[2048];
    __shared__ unsigned char kill[2048];
    __shared__ unsigned int incl[2048];
    __shared__ int changed;
    const int img = blockIdx.x;
    const int t = threadIdx.x;
    if (t < NPB) bp[t] = min(bpcnt[img * NPB + t], (unsigned int)PB_CAP);
    __syncthreads();
    if (t == 0) {
        unsigned int o = 0; ofs[0] = 0;
        for (int c = 0; c < NPB; ++c) { o += bp[c]; if (o > (unsigned int)PAIR_CAP) o = PAIR_CAP; ofs[c + 1] = o; }
    }
    for (int i = t; i < 2048; i += 1024) {
        unsigned char v = (i < PRE) ? (unsigned char)valid[img * PRE + i] : 0;
        vld[i] = v;
        alive[i] = v;
    }
    __syncthreads();
    for (int c = 0; c < NPB; ++c) {
        unsigned int b0 = ofs[c], n = ofs[c + 1] - ofs[c];
        const unsigned int* src = pairs + ((size_t)img * NPB + c) * PB_CAP;
        for (unsigned int i = t; i < n; i += 1024) pb[b0 + i] = src[i];
    }
    const int np = (int)ofs[NPB];
    __syncthreads();
    for (int iter = 0; iter < 2048; ++iter) {
        if (t == 0) changed = 0;
        for (int i = t; i < 2048; i += 1024) kill[i] = 0;
        __syncthreads();
        for (int e = t; e < np; e += 1024) {
            unsigned int u = pb[e];
            unsigned int i = u >> 11, j = u & 2047u;
            if (alive[i]) kill[j] = 1;             // benign same-value races
        }
        __syncthreads();
        for (int i = t; i < 2048; i += 1024) {
            unsigned char na = (vld[i] && !kill[i]) ? 1 : 0;
            if (na != alive[i]) { alive[i] = na; changed = 1; }
        }
        __syncthreads();
        bool done = (changed == 0);
        __syncthreads();                           // protect 'changed' vs next reset
        if (done) break;
    }
    const int i0 = t, i1 = t + 1024;
    incl[i0] = alive[i0]; incl[i1] = alive[i1];
    __syncthreads();
    for (int d = 1; d < 2048; d <<= 1) {
        unsigned int v0 = (i0 >= d) ? incl[i0 - d] : 0u;
        unsigned int v1 = (i1 >= d) ? incl[i1 - d] : 0u;
        __syncthreads();
        incl[i0] += v0; incl[i1] += v1;
        __syncthreads();
    }
    const unsigned int Nk = incl[2047];
    for (int i = t; i < PRE; i += 1024) {
        int slot = -1;
        float sc = 0.0f;
        if (alive[i]) {
            unsigned int r = incl[i] - 1u;
            if (r < (unsigned int)POST) { slot = (int)r; sc = scores[img * PRE + i]; }
        } else if (Nk < (unsigned int)POST) {
            unsigned int rnk = (unsigned int)i - incl[i];      // non-kept rank (ascending index)
            unsigned int s2 = Nk + rnk;
            if (s2 < (unsigned int)POST) { slot = (int)s2; sc = 0.0f; }
        }
        if (slot >= 0) {
            float4 b = ((const float4*)boxes)[(size_t)img * PRE + i];
            float* o = out + ((size_t)img * POST + slot) * 5;
            o[0] = b.x; o[1] = b.y; o[2] = b.z; o[3] = b.w; o[4] = sc;
        }
    }
}

extern "C" void kernel_launch(void* const* d_in, const int* in_sizes, int n_in,
                              void* d_out, int out_size, void* d_ws, size_t ws_size,
                              hipStream_t stream) {
    const float* obj = (const float*)d_in[0];
    const float* deltas = (const float*)d_in[1];
    const float* anchors = (const float*)d_in[2];
    float* out = (float*)d_out;
    const int A = in_sizes[0] / NIMG;

    char* ws = (char*)d_ws;
    unsigned int* bcnt = (unsigned int*)(ws + OFF_BCNT);
    unsigned int* bpcnt = (unsigned int*)(ws + OFF_BPCNT);
    unsigned long long* cand = (unsigned long long*)(ws + OFF_CAND);
    unsigned long long* srt = (unsigned long long*)(ws + OFF_SRT);
    float* boxes = (float*)(ws + OFF_BOX);
    float* scores = (float*)(ws + OFF_SCORE);
    unsigned int* valid = (unsigned int*)(ws + OFF_VALID);
    unsigned int* pairs = (unsigned int*)(ws + OFF_PAIRS);

    k_compact<<<dim3(NCH, NIMG), dim3(256), 0, stream>>>(obj, cand, bcnt, A);
    k_fallback<<<dim3(NIMG), dim3(1024), 0, stream>>>(obj, cand, bcnt, A);
    k_sort<<<dim3(NSORT, NIMG), dim3(1024), 0, stream>>>(cand, bcnt, srt);
    k_merge_decode<<<dim3(NSORT, NIMG), dim3(1024), 0, stream>>>(deltas, anchors, srt, boxes, scores, valid, A);
    k_pairs<<<dim3(NPB, NIMG), dim3(256), 0, stream>>>(boxes, pairs, bpcnt);
    k_final<<<dim3(NIMG), dim3(1024), 0, stream>>>(boxes, scores, valid, pairs, bpcnt, out);
}